// Round 1
// 445.180 us; speedup vs baseline: 1.0102x; 1.0102x over previous
//
#include <hip/hip_runtime.h>
#include <stdint.h>

// ---- problem constants ----
#define BT   6272      // B*T = 32*196
#define LAT  256
#define NJ3  13
#define NJ2  10
#define NJ1  20
#define NJ   43
#define D3   39
#define D2   20
#define XDIM 79        // D3+D2+D1
#define OUTROW 11008   // NJ*LAT
#define NWG  (NJ * 98) // 4214 blocks in motion_main

typedef _Float16 half8  __attribute__((ext_vector_type(8)));
typedef _Float16 half4v __attribute__((ext_vector_type(4)));
typedef float    floatx4 __attribute__((ext_vector_type(4)));

// tanh-approx gelu (matches jax.nn.gelu default approximate=True)
// gelu(h) = h - h/(exp(2u)+1), 2u = h*(1.5957691 + 0.0713548*h^2)
__device__ __forceinline__ float fast_gelu(float h) {
    float p  = h * h;
    float u2 = h * (1.5957691216057308f + 0.0713548162f * p);
    float e  = __expf(u2);
    float r  = __builtin_amdgcn_rcpf(e + 1.0f);
    return h - h * r;
}

// ---- pre-pass: W2[j][l][m] (fp32) -> W2t[j][m][l] (f16), per 64x64 tile ----
__global__ __launch_bounds__(256) void transpose_w2(
    const float* __restrict__ W2_3, const float* __restrict__ W2_2,
    const float* __restrict__ W2_1, _Float16* __restrict__ W2t)
{
    __shared__ float tile[64][65];
    const int bid = blockIdx.x;
    const int j   = bid >> 4;          // 16 tiles per joint
    const int t   = bid & 15;
    const int l0  = (t >> 2) * 64;
    const int m0  = (t & 3) * 64;

    const float* W2 = (j < NJ3) ? (W2_3 + (size_t)j * 65536)
                    : (j < NJ3 + NJ2) ? (W2_2 + (size_t)(j - NJ3) * 65536)
                    : (W2_1 + (size_t)(j - NJ3 - NJ2) * 65536);

    const int tx = threadIdx.x & 15, ty = threadIdx.x >> 4;
#pragma unroll
    for (int rr = 0; rr < 4; ++rr) {
        const int row = ty + rr * 16;
        const float4 v = *(const float4*)(W2 + (size_t)(l0 + row) * 256 + m0 + tx * 4);
        tile[row][tx * 4 + 0] = v.x;
        tile[row][tx * 4 + 1] = v.y;
        tile[row][tx * 4 + 2] = v.z;
        tile[row][tx * 4 + 3] = v.w;
    }
    __syncthreads();
#pragma unroll
    for (int rr = 0; rr < 4; ++rr) {
        const int mrow = ty + rr * 16;
        const int ll   = tx * 4;
        half4v o;
        o[0] = (_Float16)tile[ll + 0][mrow];
        o[1] = (_Float16)tile[ll + 1][mrow];
        o[2] = (_Float16)tile[ll + 2][mrow];
        o[3] = (_Float16)tile[ll + 3][mrow];
        *(half4v*)(W2t + ((size_t)j * 256 + m0 + mrow) * 256 + l0 + ll) = o;
    }
}

// ---- fused main kernel: per block = (joint j, 64-row tile) ----
// 4 waves = 1(M) x 4(N); each wave: 4x4 tiles of 16x16, K-chunks of 64.
// A (=gelu(x W1 + b1) in f16) staged in a DOUBLE-BUFFERED LDS region in
// fragment-ready layout. Software pipeline: h(kc+1) is computed in the same
// barrier-free region as the W2t loads + MFMA of chunk kc, so the ~600cy of
// VALU/trans h-work hides the ~200cy L2 latency of the B loads (and the MFMA
// pipe hides the h-work). One barrier per chunk (was two).
// h-compute is BRANCH-FREE (clamped row pointers, zeroed xv) so the whole
// chunk body is one scheduling region.
// XOR swizzle (m ^ ((slot&3)<<1)) breaks the structural 8-way bank conflict
// (unchanged from previous version; SQ_LDS_BANK_CONFLICT was ~0).
// __launch_bounds__(256,3): VGPR cap ~168, 3 blocks/CU; LDS 16KB -> 48KB/CU ok.
__global__ __launch_bounds__(256, 3) void motion_main(
    const float* __restrict__ x,
    const float* __restrict__ W1_3, const float* __restrict__ b1_3, const float* __restrict__ b2_3,
    const float* __restrict__ W1_2, const float* __restrict__ b1_2, const float* __restrict__ b2_2,
    const float* __restrict__ W1_1, const float* __restrict__ b1_1, const float* __restrict__ b2_1,
    const _Float16* __restrict__ W2t,
    float* __restrict__ out)
{
    __shared__ half8 Alds[2][512];     // [buf][slot(32)][m(16)] x 16B = 16 KB

    // bijective XCD swizzle (m204 formula; NWG=4214 not divisible by 8):
    // clusters consecutive logical tiles (same j) on one XCD so W2t[j] lives
    // in a single L2 instead of being replicated into all 8.
    const int orig = blockIdx.x;
    const int q8   = NWG >> 3, r8 = NWG & 7;
    const int xcd  = orig & 7;
    const int wgid = (xcd < r8 ? xcd * (q8 + 1)
                               : r8 * (q8 + 1) + (xcd - r8) * q8) + (orig >> 3);

    const int j   = wgid / 98;         // m-tile fastest -> same-j blocks adjacent
    const int mt  = wgid % 98;
    const int r0  = mt * 64;

    int d, xoff;
    const float *W1, *b1, *b2;
    if (j < NJ3)            { d = 3; xoff = j * 3;
                              W1 = W1_3 + j * 768;  b1 = b1_3 + j * 256;  b2 = b2_3 + j * 256; }
    else if (j < NJ3 + NJ2) { const int qj = j - NJ3; d = 2; xoff = D3 + qj * 2;
                              W1 = W1_2 + qj * 512;  b1 = b1_2 + qj * 256;  b2 = b2_2 + qj * 256; }
    else                    { const int qj = j - NJ3 - NJ2; d = 1; xoff = D3 + D2 + qj;
                              W1 = W1_1 + qj * 256;  b1 = b1_1 + qj * 256;  b2 = b2_1 + qj * 256; }

    const int tid  = threadIdx.x;
    const int rr   = tid >> 2;         // 0..63: row within the 64-row tile (h-compute role)
    const int qq   = tid & 3;          // l-quarter within chunk
    const int lane = tid & 63;
    const int wv   = tid >> 6;         // wave id 0..3 -> 64-wide N slice
    const int m16  = lane & 15;
    const int quad = lane >> 4;

    // this thread's x row stays in registers for the whole kernel
    const float* xr  = x + (size_t)(r0 + rr) * XDIM + xoff;
    const float  xv0 = xr[0];
    const float  xv1 = (d > 1) ? xr[1] : 0.0f;
    const float  xv2 = (d > 2) ? xr[2] : 0.0f;
    // branch-free W1 row pointers: absent rows alias row 0 and multiply by 0
    const float* W1r0 = W1;
    const float* W1r1 = W1 + ((d > 1) ? 256 : 0);
    const float* W1r2 = W1 + ((d > 2) ? 512 : 0);

    floatx4 acc[4][4];
#pragma unroll
    for (int i = 0; i < 4; ++i)
#pragma unroll
        for (int jj = 0; jj < 4; ++jj)
            acc[i][jj] = (floatx4){0.f, 0.f, 0.f, 0.f};

    const _Float16* W2j = W2t + (size_t)j * 65536 + (size_t)(wv * 64) * 256;

    // h-compute for chunk kc into buffer nb (branch-free, one BB)
    auto compute_h = [&](int kc, int nb) {
#pragma unroll
        for (int run = 0; run < 2; ++run) {
            const int c  = qq * 2 + run;           // 0..7: 8-wide l block in chunk
            const int l0 = kc * 64 + c * 8;
            float h[8];
#pragma unroll
            for (int u = 0; u < 8; ++u) h[u] = b1[l0 + u];
#pragma unroll
            for (int u = 0; u < 8; ++u) h[u] += xv0 * W1r0[l0 + u];
#pragma unroll
            for (int u = 0; u < 8; ++u) h[u] += xv1 * W1r1[l0 + u];
#pragma unroll
            for (int u = 0; u < 8; ++u) h[u] += xv2 * W1r2[l0 + u];
            half8 v;
#pragma unroll
            for (int u = 0; u < 8; ++u) v[u] = (_Float16)fast_gelu(h[u]);
            // slot = [i(rr>>4)][kk2(c>>2)][quad_t(c&3)], m = rr&15, XOR swizzle on m
            const int slot = (((rr >> 4) * 2 + (c >> 2)) * 4 + (c & 3));
            Alds[nb][slot * 16 + ((rr & 15) ^ ((slot & 3) << 1))] = v;
        }
    };

    // prologue: fill buffer 0
    compute_h(0, 0);
    __syncthreads();

    for (int kc = 0; kc < 4; ++kc) {
        const int b = kc & 1;
        // pipeline: next chunk's h-work issued in the same region as this
        // chunk's B loads + MFMA (independent -> scheduler interleaves)
        if (kc < 3) compute_h(kc + 1, b ^ 1);
        // ---- MFMA over chunk kc from Alds[b] ----
#pragma unroll
        for (int kk2 = 0; kk2 < 2; ++kk2) {
            half8 af[4];
#pragma unroll
            for (int i = 0; i < 4; ++i) {
                const int slot = (i * 2 + kk2) * 4 + quad;
                af[i] = Alds[b][slot * 16 + (m16 ^ ((slot & 3) << 1))];
            }
            const int kidx = kc * 64 + kk2 * 32 + quad * 8;
#pragma unroll
            for (int jj = 0; jj < 4; ++jj) {
                const half8 bf = *(const half8*)(W2j + (size_t)(jj * 16 + m16) * 256 + kidx);
#pragma unroll
                for (int i = 0; i < 4; ++i)
                    acc[i][jj] = __builtin_amdgcn_mfma_f32_16x16x32_f16(af[i], bf, acc[i][jj], 0, 0, 0);
            }
        }
        if (kc < 3) __syncthreads();   // buf b^1 complete; buf b free to overwrite
    }

    // ---- epilogue: +b2, store fp32 (C/D layout: col=lane&15, row=quad*4+reg) ----
#pragma unroll
    for (int jj = 0; jj < 4; ++jj) {
        const int n   = wv * 64 + jj * 16 + m16;
        const float b2v = b2[n];
#pragma unroll
        for (int i = 0; i < 4; ++i) {
            const int rbase = r0 + i * 16 + quad * 4;
            float* op = out + (size_t)rbase * OUTROW + (size_t)j * 256 + n;
#pragma unroll
            for (int g = 0; g < 4; ++g)
                op[(size_t)g * OUTROW] = acc[i][jj][g] + b2v;
        }
    }
}

extern "C" void kernel_launch(void* const* d_in, const int* in_sizes, int n_in,
                              void* d_out, int out_size, void* d_ws, size_t ws_size,
                              hipStream_t stream) {
    const float* x    = (const float*)d_in[0];
    const float* W1_3 = (const float*)d_in[1];
    const float* b1_3 = (const float*)d_in[2];
    const float* W2_3 = (const float*)d_in[3];
    const float* b2_3 = (const float*)d_in[4];
    const float* W1_2 = (const float*)d_in[5];
    const float* b1_2 = (const float*)d_in[6];
    const float* W2_2 = (const float*)d_in[7];
    const float* b2_2 = (const float*)d_in[8];
    const float* W1_1 = (const float*)d_in[9];
    const float* b1_1 = (const float*)d_in[10];
    const float* W2_1 = (const float*)d_in[11];
    const float* b2_1 = (const float*)d_in[12];
    float* out = (float*)d_out;
    _Float16* W2t = (_Float16*)d_ws;   // 43*256*256 f16 = 5.64 MB, rebuilt every call

    transpose_w2<<<NJ * 16, 256, 0, stream>>>(W2_3, W2_2, W2_1, W2t);
    motion_main<<<NWG, 256, 0, stream>>>(x, W1_3, b1_3, b2_3,
                                         W1_2, b1_2, b2_2,
                                         W1_1, b1_1, b2_1, W2t, out);
}

// Round 2
// 402.263 us; speedup vs baseline: 1.1180x; 1.1067x over previous
//
#include <hip/hip_runtime.h>
#include <stdint.h>

// ---- problem constants ----
#define BT   6272      // B*T = 32*196
#define LAT  256
#define NJ3  13
#define NJ2  10
#define NJ1  20
#define NJ   43
#define D3   39
#define D2   20
#define XDIM 79        // D3+D2+D1
#define OUTROW 11008   // NJ*LAT
#define NWG  (NJ * 98) // 4214 blocks in motion_main

typedef _Float16 half8  __attribute__((ext_vector_type(8)));
typedef _Float16 half4v __attribute__((ext_vector_type(4)));
typedef float    floatx4 __attribute__((ext_vector_type(4)));

// tanh-approx gelu (matches jax.nn.gelu default approximate=True)
// gelu(h) = h - h/(exp(2u)+1), 2u = h*(1.5957691 + 0.0713548*h^2)
// log2(e) folded into the polynomial so we can use raw v_exp_f32 (exp2):
//   2.302216... = 1.5957691216 * log2e ; 0.10294357 = 0.0713548162 * log2e
__device__ __forceinline__ float fast_gelu(float h) {
    float p  = h * h;
    float u2 = h * (2.3022164464f + 0.1029435704f * p);
    float e  = __builtin_amdgcn_exp2f(u2);
    float r  = __builtin_amdgcn_rcpf(e + 1.0f);
    return h - h * r;
}

// ---- pre-pass: W2[j][l][m] (fp32) -> W2t[j][m][l] (f16), per 64x64 tile ----
__global__ __launch_bounds__(256) void transpose_w2(
    const float* __restrict__ W2_3, const float* __restrict__ W2_2,
    const float* __restrict__ W2_1, _Float16* __restrict__ W2t)
{
    __shared__ float tile[64][65];
    const int bid = blockIdx.x;
    const int j   = bid >> 4;          // 16 tiles per joint
    const int t   = bid & 15;
    const int l0  = (t >> 2) * 64;
    const int m0  = (t & 3) * 64;

    const float* W2 = (j < NJ3) ? (W2_3 + (size_t)j * 65536)
                    : (j < NJ3 + NJ2) ? (W2_2 + (size_t)(j - NJ3) * 65536)
                    : (W2_1 + (size_t)(j - NJ3 - NJ2) * 65536);

    const int tx = threadIdx.x & 15, ty = threadIdx.x >> 4;
#pragma unroll
    for (int rr = 0; rr < 4; ++rr) {
        const int row = ty + rr * 16;
        const float4 v = *(const float4*)(W2 + (size_t)(l0 + row) * 256 + m0 + tx * 4);
        tile[row][tx * 4 + 0] = v.x;
        tile[row][tx * 4 + 1] = v.y;
        tile[row][tx * 4 + 2] = v.z;
        tile[row][tx * 4 + 3] = v.w;
    }
    __syncthreads();
#pragma unroll
    for (int rr = 0; rr < 4; ++rr) {
        const int mrow = ty + rr * 16;
        const int ll   = tx * 4;
        half4v o;
        o[0] = (_Float16)tile[ll + 0][mrow];
        o[1] = (_Float16)tile[ll + 1][mrow];
        o[2] = (_Float16)tile[ll + 2][mrow];
        o[3] = (_Float16)tile[ll + 3][mrow];
        *(half4v*)(W2t + ((size_t)j * 256 + m0 + mrow) * 256 + l0 + ll) = o;
    }
}

// ---- fused main kernel: per block = (joint j, 64-row tile) ----
// 4 waves = 1(M) x 4(N); each wave: 4x4 tiles of 16x16, K-chunks of 64.
// A (=gelu(x W1 + b1) in f16) staged in a DOUBLE-BUFFERED LDS region in
// fragment-ready layout; one barrier per chunk; h(kc+1) overlapped with
// MFMA(kc).
// NEW this round: W1/b1 staged in LDS ONCE per block (5 KB, coalesced) --
// h-compute previously issued 256 per-lane global dword loads per thread
// (b1/W1 re-read from L1 each run, only 4 distinct addrs per wave); now it
// is 64 ds_read_b128 (broadcast within qq-groups / 2-way => free per m136).
// Per-thread VMEM instruction count drops ~355 -> ~107.
// XOR swizzle (m ^ ((slot&3)<<1)) on Alds unchanged (bank conflicts ~0).
// __launch_bounds__(256,3): VGPR cap ~168, 3 blocks/CU; LDS 21KB -> 63KB/CU.
__global__ __launch_bounds__(256, 3) void motion_main(
    const float* __restrict__ x,
    const float* __restrict__ W1_3, const float* __restrict__ b1_3, const float* __restrict__ b2_3,
    const float* __restrict__ W1_2, const float* __restrict__ b1_2, const float* __restrict__ b2_2,
    const float* __restrict__ W1_1, const float* __restrict__ b1_1, const float* __restrict__ b2_1,
    const _Float16* __restrict__ W2t,
    float* __restrict__ out)
{
    __shared__ half8 Alds[2][512];     // [buf][slot(32)][m(16)] x 16B = 16 KB
    __shared__ float W1s[3 * 256];     // 3 KB  (rows alias row0 when d<3; xv=0 kills them)
    __shared__ float b1s[256];         // 1 KB

    // bijective XCD swizzle (m204 formula; NWG=4214 not divisible by 8):
    // clusters consecutive logical tiles (same j) on one XCD so W2t[j] lives
    // in a single L2 instead of being replicated into all 8.
    const int orig = blockIdx.x;
    const int q8   = NWG >> 3, r8 = NWG & 7;
    const int xcd  = orig & 7;
    const int wgid = (xcd < r8 ? xcd * (q8 + 1)
                               : r8 * (q8 + 1) + (xcd - r8) * q8) + (orig >> 3);

    const int j   = wgid / 98;         // m-tile fastest -> same-j blocks adjacent
    const int mt  = wgid % 98;
    const int r0  = mt * 64;

    int d, xoff;
    const float *W1, *b1, *b2;
    if (j < NJ3)            { d = 3; xoff = j * 3;
                              W1 = W1_3 + j * 768;  b1 = b1_3 + j * 256;  b2 = b2_3 + j * 256; }
    else if (j < NJ3 + NJ2) { const int qj = j - NJ3; d = 2; xoff = D3 + qj * 2;
                              W1 = W1_2 + qj * 512;  b1 = b1_2 + qj * 256;  b2 = b2_2 + qj * 256; }
    else                    { const int qj = j - NJ3 - NJ2; d = 1; xoff = D3 + D2 + qj;
                              W1 = W1_1 + qj * 256;  b1 = b1_1 + qj * 256;  b2 = b2_1 + qj * 256; }

    const int tid  = threadIdx.x;
    const int rr   = tid >> 2;         // 0..63: row within the 64-row tile (h-compute role)
    const int qq   = tid & 3;          // l-quarter within chunk
    const int lane = tid & 63;
    const int wv   = tid >> 6;         // wave id 0..3 -> 64-wide N slice
    const int m16  = lane & 15;
    const int quad = lane >> 4;

    // branch-free W1 row pointers: absent rows alias row 0 and multiply by 0
    const float* W1r0 = W1;
    const float* W1r1 = W1 + ((d > 1) ? 256 : 0);
    const float* W1r2 = W1 + ((d > 2) ? 512 : 0);

    // ---- stage W1 (3 rows) + b1 into LDS, coalesced float4 ----
    if (tid < 192) {
        const float* src = (tid < 64) ? W1r0 : (tid < 128) ? W1r1 : W1r2;
        const int o = (tid & 63) * 4;
        *(float4*)(W1s + (tid >> 6) * 256 + o) = *(const float4*)(src + o);
    } else {
        const int o = (tid - 192) * 4;
        *(float4*)(b1s + o) = *(const float4*)(b1 + o);
    }

    // this thread's x row stays in registers for the whole kernel
    const float* xr  = x + (size_t)(r0 + rr) * XDIM + xoff;
    const float  xv0 = xr[0];
    const float  xv1 = (d > 1) ? xr[1] : 0.0f;
    const float  xv2 = (d > 2) ? xr[2] : 0.0f;

    floatx4 acc[4][4];
#pragma unroll
    for (int i = 0; i < 4; ++i)
#pragma unroll
        for (int jj = 0; jj < 4; ++jj)
            acc[i][jj] = (floatx4){0.f, 0.f, 0.f, 0.f};

    const _Float16* W2j = W2t + (size_t)j * 65536 + (size_t)(wv * 64) * 256;

    // h-compute for chunk kc into buffer nb (branch-free, reads W1/b1 from LDS)
    auto compute_h = [&](int kc, int nb) {
#pragma unroll
        for (int run = 0; run < 2; ++run) {
            const int c  = qq * 2 + run;           // 0..7: 8-wide l block in chunk
            const int l0 = kc * 64 + c * 8;
            float h[8];
#pragma unroll
            for (int u = 0; u < 8; ++u) h[u] = b1s[l0 + u];
#pragma unroll
            for (int u = 0; u < 8; ++u) h[u] += xv0 * W1s[l0 + u];
#pragma unroll
            for (int u = 0; u < 8; ++u) h[u] += xv1 * W1s[256 + l0 + u];
#pragma unroll
            for (int u = 0; u < 8; ++u) h[u] += xv2 * W1s[512 + l0 + u];
            half8 v;
#pragma unroll
            for (int u = 0; u < 8; ++u) v[u] = (_Float16)fast_gelu(h[u]);
            // slot = [i(rr>>4)][kk2(c>>2)][quad_t(c&3)], m = rr&15, XOR swizzle on m
            const int slot = (((rr >> 4) * 2 + (c >> 2)) * 4 + (c & 3));
            Alds[nb][slot * 16 + ((rr & 15) ^ ((slot & 3) << 1))] = v;
        }
    };

    __syncthreads();                   // W1s/b1s visible
    // prologue: fill buffer 0
    compute_h(0, 0);
    __syncthreads();

    for (int kc = 0; kc < 4; ++kc) {
        const int b = kc & 1;
        // pipeline: next chunk's h-work issued in the same region as this
        // chunk's B loads + MFMA (independent -> scheduler interleaves)
        if (kc < 3) compute_h(kc + 1, b ^ 1);
        // ---- MFMA over chunk kc from Alds[b] ----
#pragma unroll
        for (int kk2 = 0; kk2 < 2; ++kk2) {
            half8 af[4];
#pragma unroll
            for (int i = 0; i < 4; ++i) {
                const int slot = (i * 2 + kk2) * 4 + quad;
                af[i] = Alds[b][slot * 16 + (m16 ^ ((slot & 3) << 1))];
            }
            const int kidx = kc * 64 + kk2 * 32 + quad * 8;
#pragma unroll
            for (int jj = 0; jj < 4; ++jj) {
                const half8 bf = *(const half8*)(W2j + (size_t)(jj * 16 + m16) * 256 + kidx);
#pragma unroll
                for (int i = 0; i < 4; ++i)
                    acc[i][jj] = __builtin_amdgcn_mfma_f32_16x16x32_f16(af[i], bf, acc[i][jj], 0, 0, 0);
            }
        }
        if (kc < 3) __syncthreads();   // buf b^1 complete; buf b free to overwrite
    }

    // ---- epilogue: +b2, store fp32 (C/D layout: col=lane&15, row=quad*4+reg) ----
#pragma unroll
    for (int jj = 0; jj < 4; ++jj) {
        const int n   = wv * 64 + jj * 16 + m16;
        const float b2v = b2[n];
#pragma unroll
        for (int i = 0; i < 4; ++i) {
            const int rbase = r0 + i * 16 + quad * 4;
            float* op = out + (size_t)rbase * OUTROW + (size_t)j * 256 + n;
#pragma unroll
            for (int g = 0; g < 4; ++g)
                op[(size_t)g * OUTROW] = acc[i][jj][g] + b2v;
        }
    }
}

extern "C" void kernel_launch(void* const* d_in, const int* in_sizes, int n_in,
                              void* d_out, int out_size, void* d_ws, size_t ws_size,
                              hipStream_t stream) {
    const float* x    = (const float*)d_in[0];
    const float* W1_3 = (const float*)d_in[1];
    const float* b1_3 = (const float*)d_in[2];
    const float* W2_3 = (const float*)d_in[3];
    const float* b2_3 = (const float*)d_in[4];
    const float* W1_2 = (const float*)d_in[5];
    const float* b1_2 = (const float*)d_in[6];
    const float* W2_2 = (const float*)d_in[7];
    const float* b2_2 = (const float*)d_in[8];
    const float* W1_1 = (const float*)d_in[9];
    const float* b1_1 = (const float*)d_in[10];
    const float* W2_1 = (const float*)d_in[11];
    const float* b2_1 = (const float*)d_in[12];
    float* out = (float*)d_out;
    _Float16* W2t = (_Float16*)d_ws;   // 43*256*256 f16 = 5.64 MB, rebuilt every call

    transpose_w2<<<NJ * 16, 256, 0, stream>>>(W2_3, W2_2, W2_1, W2t);
    motion_main<<<NWG, 256, 0, stream>>>(x, W1_3, b1_3, b2_3,
                                         W1_2, b1_2, b2_2,
                                         W1_1, b1_1, b2_1, W2t, out);
}

// Round 3
// 393.864 us; speedup vs baseline: 1.1418x; 1.0213x over previous
//
#include <hip/hip_runtime.h>
#include <stdint.h>

// ---- problem constants ----
#define BT   6272      // B*T = 32*196
#define LAT  256
#define NJ3  13
#define NJ2  10
#define NJ1  20
#define NJ   43
#define D3   39
#define D2   20
#define XDIM 79        // D3+D2+D1
#define OUTROW 11008   // NJ*LAT
#define NWG  (NJ * 98) // 4214 blocks in motion_main

typedef _Float16 half8  __attribute__((ext_vector_type(8)));
typedef _Float16 half4v __attribute__((ext_vector_type(4)));
typedef float    floatx4 __attribute__((ext_vector_type(4)));

// tanh-approx gelu (matches jax.nn.gelu default approximate=True)
// gelu(h) = h - h/(exp(2u)+1), 2u = h*(1.5957691 + 0.0713548*h^2)
// log2(e) folded into the polynomial so we can use raw v_exp_f32 (exp2):
__device__ __forceinline__ float fast_gelu(float h) {
    float p  = h * h;
    float u2 = h * (2.3022164464f + 0.1029435704f * p);
    float e  = __builtin_amdgcn_exp2f(u2);
    float r  = __builtin_amdgcn_rcpf(e + 1.0f);
    return h - h * r;
}

// ---- pre-pass: W2[j][l][m] (fp32) -> W2t[j][m][l] (f16), per 64x64 tile ----
__global__ __launch_bounds__(256) void transpose_w2(
    const float* __restrict__ W2_3, const float* __restrict__ W2_2,
    const float* __restrict__ W2_1, _Float16* __restrict__ W2t)
{
    __shared__ float tile[64][65];
    const int bid = blockIdx.x;
    const int j   = bid >> 4;          // 16 tiles per joint
    const int t   = bid & 15;
    const int l0  = (t >> 2) * 64;
    const int m0  = (t & 3) * 64;

    const float* W2 = (j < NJ3) ? (W2_3 + (size_t)j * 65536)
                    : (j < NJ3 + NJ2) ? (W2_2 + (size_t)(j - NJ3) * 65536)
                    : (W2_1 + (size_t)(j - NJ3 - NJ2) * 65536);

    const int tx = threadIdx.x & 15, ty = threadIdx.x >> 4;
#pragma unroll
    for (int rr = 0; rr < 4; ++rr) {
        const int row = ty + rr * 16;
        const float4 v = *(const float4*)(W2 + (size_t)(l0 + row) * 256 + m0 + tx * 4);
        tile[row][tx * 4 + 0] = v.x;
        tile[row][tx * 4 + 1] = v.y;
        tile[row][tx * 4 + 2] = v.z;
        tile[row][tx * 4 + 3] = v.w;
    }
    __syncthreads();
#pragma unroll
    for (int rr = 0; rr < 4; ++rr) {
        const int mrow = ty + rr * 16;
        const int ll   = tx * 4;
        half4v o;
        o[0] = (_Float16)tile[ll + 0][mrow];
        o[1] = (_Float16)tile[ll + 1][mrow];
        o[2] = (_Float16)tile[ll + 2][mrow];
        o[3] = (_Float16)tile[ll + 3][mrow];
        *(half4v*)(W2t + ((size_t)j * 256 + m0 + mrow) * 256 + l0 + ll) = o;
    }
}

// ---- fused main kernel: per block = (joint j, 64-row tile) ----
// 4 waves = 1(M) x 4(N); each wave: 4x4 tiles of 16x16, K-chunks of 64.
// A (=gelu(x W1 + b1) in f16) double-buffered in LDS; one barrier per chunk;
// h(kc+1) overlapped with MFMA(kc); W1/b1 staged in LDS once per block.
// NEW this round: MFMA operands SWAPPED -- mfma(bf, af) computes the
// transposed tile, so each lane holds 4 CONSECUTIVE n-values per row
// (D: col(lane&15)=m-row, row(quad*4+reg)=n-col). Epilogue becomes 16
// float4 stores (16 full 64B lines per inst) instead of 64 scalar stores.
// A/B fragment layouts are symmetric for 16x16x32 f16 (lane&15=row/col,
// lane>>4=k-group), so the same register data is valid in swapped slots;
// summation order unchanged -> bit-identical result.
// s_setprio(1) wraps the MFMA cluster (3 independently-phased blocks/CU:
// the regime where setprio paid on attn, m191).
// __launch_bounds__(256,3): VGPR cap ~168, 3 blocks/CU; LDS 20.5KB/block.
__global__ __launch_bounds__(256, 3) void motion_main(
    const float* __restrict__ x,
    const float* __restrict__ W1_3, const float* __restrict__ b1_3, const float* __restrict__ b2_3,
    const float* __restrict__ W1_2, const float* __restrict__ b1_2, const float* __restrict__ b2_2,
    const float* __restrict__ W1_1, const float* __restrict__ b1_1, const float* __restrict__ b2_1,
    const _Float16* __restrict__ W2t,
    float* __restrict__ out)
{
    __shared__ half8 Alds[2][512];     // [buf][slot(32)][m(16)] x 16B = 16 KB
    __shared__ float W1s[3 * 256];     // 3 KB  (rows alias row0 when d<3; xv=0 kills them)
    __shared__ float b1s[256];         // 1 KB

    // bijective XCD swizzle (m204 formula; NWG=4214 not divisible by 8)
    const int orig = blockIdx.x;
    const int q8   = NWG >> 3, r8 = NWG & 7;
    const int xcd  = orig & 7;
    const int wgid = (xcd < r8 ? xcd * (q8 + 1)
                               : r8 * (q8 + 1) + (xcd - r8) * q8) + (orig >> 3);

    const int j   = wgid / 98;         // m-tile fastest -> same-j blocks adjacent
    const int mt  = wgid % 98;
    const int r0  = mt * 64;

    int d, xoff;
    const float *W1, *b1, *b2;
    if (j < NJ3)            { d = 3; xoff = j * 3;
                              W1 = W1_3 + j * 768;  b1 = b1_3 + j * 256;  b2 = b2_3 + j * 256; }
    else if (j < NJ3 + NJ2) { const int qj = j - NJ3; d = 2; xoff = D3 + qj * 2;
                              W1 = W1_2 + qj * 512;  b1 = b1_2 + qj * 256;  b2 = b2_2 + qj * 256; }
    else                    { const int qj = j - NJ3 - NJ2; d = 1; xoff = D3 + D2 + qj;
                              W1 = W1_1 + qj * 256;  b1 = b1_1 + qj * 256;  b2 = b2_1 + qj * 256; }

    const int tid  = threadIdx.x;
    const int rr   = tid >> 2;         // 0..63: row within the 64-row tile (h-compute role)
    const int qq   = tid & 3;          // l-quarter within chunk
    const int lane = tid & 63;
    const int wv   = tid >> 6;         // wave id 0..3 -> 64-wide N slice
    const int m16  = lane & 15;
    const int quad = lane >> 4;

    // branch-free W1 row pointers: absent rows alias row 0 and multiply by 0
    const float* W1r0 = W1;
    const float* W1r1 = W1 + ((d > 1) ? 256 : 0);
    const float* W1r2 = W1 + ((d > 2) ? 512 : 0);

    // ---- stage W1 (3 rows) + b1 into LDS, coalesced float4 ----
    if (tid < 192) {
        const float* src = (tid < 64) ? W1r0 : (tid < 128) ? W1r1 : W1r2;
        const int o = (tid & 63) * 4;
        *(float4*)(W1s + (tid >> 6) * 256 + o) = *(const float4*)(src + o);
    } else {
        const int o = (tid - 192) * 4;
        *(float4*)(b1s + o) = *(const float4*)(b1 + o);
    }

    // this thread's x row stays in registers for the whole kernel
    const float* xr  = x + (size_t)(r0 + rr) * XDIM + xoff;
    const float  xv0 = xr[0];
    const float  xv1 = (d > 1) ? xr[1] : 0.0f;
    const float  xv2 = (d > 2) ? xr[2] : 0.0f;

    floatx4 acc[4][4];
#pragma unroll
    for (int i = 0; i < 4; ++i)
#pragma unroll
        for (int jj = 0; jj < 4; ++jj)
            acc[i][jj] = (floatx4){0.f, 0.f, 0.f, 0.f};

    const _Float16* W2j = W2t + (size_t)j * 65536 + (size_t)(wv * 64) * 256;

    // h-compute for chunk kc into buffer nb (branch-free, reads W1/b1 from LDS)
    auto compute_h = [&](int kc, int nb) {
#pragma unroll
        for (int run = 0; run < 2; ++run) {
            const int c  = qq * 2 + run;           // 0..7: 8-wide l block in chunk
            const int l0 = kc * 64 + c * 8;
            float h[8];
#pragma unroll
            for (int u = 0; u < 8; ++u) h[u] = b1s[l0 + u];
#pragma unroll
            for (int u = 0; u < 8; ++u) h[u] += xv0 * W1s[l0 + u];
#pragma unroll
            for (int u = 0; u < 8; ++u) h[u] += xv1 * W1s[256 + l0 + u];
#pragma unroll
            for (int u = 0; u < 8; ++u) h[u] += xv2 * W1s[512 + l0 + u];
            half8 v;
#pragma unroll
            for (int u = 0; u < 8; ++u) v[u] = (_Float16)fast_gelu(h[u]);
            // slot = [i(rr>>4)][kk2(c>>2)][quad_t(c&3)], m = rr&15, XOR swizzle on m
            const int slot = (((rr >> 4) * 2 + (c >> 2)) * 4 + (c & 3));
            Alds[nb][slot * 16 + ((rr & 15) ^ ((slot & 3) << 1))] = v;
        }
    };

    __syncthreads();                   // W1s/b1s visible
    // prologue: fill buffer 0
    compute_h(0, 0);
    __syncthreads();

    for (int kc = 0; kc < 4; ++kc) {
        const int b = kc & 1;
        // pipeline: next chunk's h-work issued in the same region as this
        // chunk's B loads + MFMA (independent -> scheduler interleaves)
        if (kc < 3) compute_h(kc + 1, b ^ 1);
        // ---- MFMA over chunk kc from Alds[b] ----
#pragma unroll
        for (int kk2 = 0; kk2 < 2; ++kk2) {
            half8 af[4];
#pragma unroll
            for (int i = 0; i < 4; ++i) {
                const int slot = (i * 2 + kk2) * 4 + quad;
                af[i] = Alds[b][slot * 16 + (m16 ^ ((slot & 3) << 1))];
            }
            const int kidx = kc * 64 + kk2 * 32 + quad * 8;
            __builtin_amdgcn_s_setprio(1);
#pragma unroll
            for (int jj = 0; jj < 4; ++jj) {
                const half8 bf = *(const half8*)(W2j + (size_t)(jj * 16 + m16) * 256 + kidx);
#pragma unroll
                for (int i = 0; i < 4; ++i)
                    acc[i][jj] = __builtin_amdgcn_mfma_f32_16x16x32_f16(bf, af[i], acc[i][jj], 0, 0, 0);
            }
            __builtin_amdgcn_s_setprio(0);
        }
        if (kc < 3) __syncthreads();   // buf b^1 complete; buf b free to overwrite
    }

    // ---- epilogue: +b2, float4 stores ----
    // swapped-D layout: lane(m16,quad), reg g holds out[r0+i*16+m16][wv*64+jj*16+quad*4+g]
    float4 b2q[4];
#pragma unroll
    for (int jj = 0; jj < 4; ++jj)
        b2q[jj] = *(const float4*)(b2 + wv * 64 + jj * 16 + quad * 4);

    const size_t colbase = (size_t)j * 256 + wv * 64 + quad * 4;
#pragma unroll
    for (int i = 0; i < 4; ++i) {
        float* orow = out + (size_t)(r0 + i * 16 + m16) * OUTROW + colbase;
#pragma unroll
        for (int jj = 0; jj < 4; ++jj) {
            float4 v;
            v.x = acc[i][jj][0] + b2q[jj].x;
            v.y = acc[i][jj][1] + b2q[jj].y;
            v.z = acc[i][jj][2] + b2q[jj].z;
            v.w = acc[i][jj][3] + b2q[jj].w;
            *(float4*)(orow + jj * 16) = v;
        }
    }
}

extern "C" void kernel_launch(void* const* d_in, const int* in_sizes, int n_in,
                              void* d_out, int out_size, void* d_ws, size_t ws_size,
                              hipStream_t stream) {
    const float* x    = (const float*)d_in[0];
    const float* W1_3 = (const float*)d_in[1];
    const float* b1_3 = (const float*)d_in[2];
    const float* W2_3 = (const float*)d_in[3];
    const float* b2_3 = (const float*)d_in[4];
    const float* W1_2 = (const float*)d_in[5];
    const float* b1_2 = (const float*)d_in[6];
    const float* W2_2 = (const float*)d_in[7];
    const float* b2_2 = (const float*)d_in[8];
    const float* W1_1 = (const float*)d_in[9];
    const float* b1_1 = (const float*)d_in[10];
    const float* W2_1 = (const float*)d_in[11];
    const float* b2_1 = (const float*)d_in[12];
    float* out = (float*)d_out;
    _Float16* W2t = (_Float16*)d_ws;   // 43*256*256 f16 = 5.64 MB, rebuilt every call

    transpose_w2<<<NJ * 16, 256, 0, stream>>>(W2_3, W2_2, W2_1, W2t);
    motion_main<<<NWG, 256, 0, stream>>>(x, W1_3, b1_3, b2_3,
                                         W1_2, b1_2, b2_2,
                                         W1_1, b1_1, b2_1, W2t, out);
}

// Round 5
// 381.784 us; speedup vs baseline: 1.1780x; 1.0316x over previous
//
#include <hip/hip_runtime.h>
#include <stdint.h>

// ---- problem constants ----
#define BT   6272      // B*T = 32*196
#define LAT  256
#define NJ3  13
#define NJ2  10
#define NJ1  20
#define NJ   43
#define D3   39
#define D2   20
#define XDIM 79        // D3+D2+D1
#define OUTROW 11008   // NJ*LAT
#define NWG  (NJ * 98) // 4214 blocks in motion_main

typedef _Float16 half8  __attribute__((ext_vector_type(8)));
typedef _Float16 half4v __attribute__((ext_vector_type(4)));
typedef float    floatx4 __attribute__((ext_vector_type(4)));

// tanh-approx gelu (matches jax.nn.gelu default approximate=True)
// gelu(h) = h - h/(exp(2u)+1), 2u = h*(1.5957691 + 0.0713548*h^2)
// log2(e) folded into the polynomial so we can use raw v_exp_f32 (exp2):
__device__ __forceinline__ float fast_gelu(float h) {
    float p  = h * h;
    float u2 = h * (2.3022164464f + 0.1029435704f * p);
    float e  = __builtin_amdgcn_exp2f(u2);
    float r  = __builtin_amdgcn_rcpf(e + 1.0f);
    return h - h * r;
}

// ---- pre-pass: W2[j][l][m] (fp32) -> W2t[j][m][l] (f16), per 64x64 tile ----
__global__ __launch_bounds__(256) void transpose_w2(
    const float* __restrict__ W2_3, const float* __restrict__ W2_2,
    const float* __restrict__ W2_1, _Float16* __restrict__ W2t)
{
    __shared__ float tile[64][65];
    const int bid = blockIdx.x;
    const int j   = bid >> 4;          // 16 tiles per joint
    const int t   = bid & 15;
    const int l0  = (t >> 2) * 64;
    const int m0  = (t & 3) * 64;

    const float* W2 = (j < NJ3) ? (W2_3 + (size_t)j * 65536)
                    : (j < NJ3 + NJ2) ? (W2_2 + (size_t)(j - NJ3) * 65536)
                    : (W2_1 + (size_t)(j - NJ3 - NJ2) * 65536);

    const int tx = threadIdx.x & 15, ty = threadIdx.x >> 4;
#pragma unroll
    for (int rr = 0; rr < 4; ++rr) {
        const int row = ty + rr * 16;
        const float4 v = *(const float4*)(W2 + (size_t)(l0 + row) * 256 + m0 + tx * 4);
        tile[row][tx * 4 + 0] = v.x;
        tile[row][tx * 4 + 1] = v.y;
        tile[row][tx * 4 + 2] = v.z;
        tile[row][tx * 4 + 3] = v.w;
    }
    __syncthreads();
#pragma unroll
    for (int rr = 0; rr < 4; ++rr) {
        const int mrow = ty + rr * 16;
        const int ll   = tx * 4;
        half4v o;
        o[0] = (_Float16)tile[ll + 0][mrow];
        o[1] = (_Float16)tile[ll + 1][mrow];
        o[2] = (_Float16)tile[ll + 2][mrow];
        o[3] = (_Float16)tile[ll + 3][mrow];
        *(half4v*)(W2t + ((size_t)j * 256 + m0 + mrow) * 256 + l0 + ll) = o;
    }
}

// ---- fused main kernel: per block = (joint j, 64-row tile) ----
// 8 waves x 512 threads per block. Each wave owns a 32-wide n-slice
// (acc = 4x2 tiles = 32 VGPR), h-compute is 1 run/chunk. Per-thread peak
// VGPR ~110 -> __launch_bounds__(512,4) caps at 128 without spilling ->
// 4 waves/SIMD (16 waves/CU), +33% TLP vs round-3's 3 waves/SIMD.
// Theory: remaining ~2x over the store-BW floor is unhidden latency
// (LDS->MFMA chain + store bursts) that 3-deep TLP can't cover.
// Nontemporal output stores (via ext_vector floatx4 -- the builtin rejects
// HIP_vector_type float4): 276 MB of streaming writes were flushing W2t
// (5.6 MB, ~700KB/XCD after the j-cluster swizzle) out of L2 every round.
// Unchanged: double-buffered Alds + one barrier per chunk, h(kc+1) in the
// same region as MFMA(kc); W1/b1 staged in LDS; swapped mfma(bf,af) so the
// epilogue is float4 row-stores; XOR swizzle on Alds; bijective XCD swizzle;
// s_setprio(1) around the MFMA cluster.
__global__ __launch_bounds__(512, 4) void motion_main(
    const float* __restrict__ x,
    const float* __restrict__ W1_3, const float* __restrict__ b1_3, const float* __restrict__ b2_3,
    const float* __restrict__ W1_2, const float* __restrict__ b1_2, const float* __restrict__ b2_2,
    const float* __restrict__ W1_1, const float* __restrict__ b1_1, const float* __restrict__ b2_1,
    const _Float16* __restrict__ W2t,
    float* __restrict__ out)
{
    __shared__ half8 Alds[2][512];     // [buf][slot(32)][m(16)] x 16B = 16 KB
    __shared__ float W1s[3 * 256];     // 3 KB  (rows alias row0 when d<3; xv=0 kills them)
    __shared__ float b1s[256];         // 1 KB

    // bijective XCD swizzle (m204 formula; NWG=4214 not divisible by 8)
    const int orig = blockIdx.x;
    const int q8   = NWG >> 3, r8 = NWG & 7;
    const int xcd  = orig & 7;
    const int wgid = (xcd < r8 ? xcd * (q8 + 1)
                               : r8 * (q8 + 1) + (xcd - r8) * q8) + (orig >> 3);

    const int j   = wgid / 98;         // m-tile fastest -> same-j blocks adjacent
    const int mt  = wgid % 98;
    const int r0  = mt * 64;

    int d, xoff;
    const float *W1, *b1, *b2;
    if (j < NJ3)            { d = 3; xoff = j * 3;
                              W1 = W1_3 + j * 768;  b1 = b1_3 + j * 256;  b2 = b2_3 + j * 256; }
    else if (j < NJ3 + NJ2) { const int qj = j - NJ3; d = 2; xoff = D3 + qj * 2;
                              W1 = W1_2 + qj * 512;  b1 = b1_2 + qj * 256;  b2 = b2_2 + qj * 256; }
    else                    { const int qj = j - NJ3 - NJ2; d = 1; xoff = D3 + D2 + qj;
                              W1 = W1_1 + qj * 256;  b1 = b1_1 + qj * 256;  b2 = b2_1 + qj * 256; }

    const int tid  = threadIdx.x;
    const int rr   = tid >> 3;         // 0..63: row within the 64-row tile (h-compute role)
    const int qq   = tid & 7;          // c-index: 8-wide l block within chunk
    const int lane = tid & 63;
    const int wv   = tid >> 6;         // wave id 0..7 -> 32-wide N slice
    const int m16  = lane & 15;
    const int quad = lane >> 4;

    // branch-free W1 row pointers: absent rows alias row 0 and multiply by 0
    const float* W1r0 = W1;
    const float* W1r1 = W1 + ((d > 1) ? 256 : 0);
    const float* W1r2 = W1 + ((d > 2) ? 512 : 0);

    // ---- stage W1 (3 rows) + b1 into LDS, coalesced float4 ----
    if (tid < 192) {
        const float* src = (tid < 64) ? W1r0 : (tid < 128) ? W1r1 : W1r2;
        const int o = (tid & 63) * 4;
        *(float4*)(W1s + (tid >> 6) * 256 + o) = *(const float4*)(src + o);
    } else if (tid < 256) {
        const int o = (tid - 192) * 4;
        *(float4*)(b1s + o) = *(const float4*)(b1 + o);
    }

    // this thread's x row stays in registers for the whole kernel
    const float* xr  = x + (size_t)(r0 + rr) * XDIM + xoff;
    const float  xv0 = xr[0];
    const float  xv1 = (d > 1) ? xr[1] : 0.0f;
    const float  xv2 = (d > 2) ? xr[2] : 0.0f;

    floatx4 acc[4][2];
#pragma unroll
    for (int i = 0; i < 4; ++i)
#pragma unroll
        for (int jj = 0; jj < 2; ++jj)
            acc[i][jj] = (floatx4){0.f, 0.f, 0.f, 0.f};

    const _Float16* W2j = W2t + (size_t)j * 65536 + (size_t)(wv * 32) * 256;

    // h-compute for chunk kc into buffer nb (branch-free, reads W1/b1 from LDS)
    // 512 threads -> one 8-wide l block per thread per chunk (c = qq)
    auto compute_h = [&](int kc, int nb) {
        const int c  = qq;
        const int l0 = kc * 64 + c * 8;
        float h[8];
#pragma unroll
        for (int u = 0; u < 8; ++u) h[u] = b1s[l0 + u];
#pragma unroll
        for (int u = 0; u < 8; ++u) h[u] += xv0 * W1s[l0 + u];
#pragma unroll
        for (int u = 0; u < 8; ++u) h[u] += xv1 * W1s[256 + l0 + u];
#pragma unroll
        for (int u = 0; u < 8; ++u) h[u] += xv2 * W1s[512 + l0 + u];
        half8 v;
#pragma unroll
        for (int u = 0; u < 8; ++u) v[u] = (_Float16)fast_gelu(h[u]);
        // slot = [i(rr>>4)][kk2(c>>2)][quad_t(c&3)], m = rr&15, XOR swizzle on m
        const int slot = (((rr >> 4) * 2 + (c >> 2)) * 4 + (c & 3));
        Alds[nb][slot * 16 + ((rr & 15) ^ ((slot & 3) << 1))] = v;
    };

    __syncthreads();                   // W1s/b1s visible
    // prologue: fill buffer 0
    compute_h(0, 0);
    __syncthreads();

    for (int kc = 0; kc < 4; ++kc) {
        const int b = kc & 1;
        // pipeline: next chunk's h-work issued in the same region as this
        // chunk's B loads + MFMA (independent -> scheduler interleaves)
        if (kc < 3) compute_h(kc + 1, b ^ 1);
        // ---- MFMA over chunk kc from Alds[b] ----
#pragma unroll
        for (int kk2 = 0; kk2 < 2; ++kk2) {
            half8 af[4];
#pragma unroll
            for (int i = 0; i < 4; ++i) {
                const int slot = (i * 2 + kk2) * 4 + quad;
                af[i] = Alds[b][slot * 16 + (m16 ^ ((slot & 3) << 1))];
            }
            const int kidx = kc * 64 + kk2 * 32 + quad * 8;
            __builtin_amdgcn_s_setprio(1);
#pragma unroll
            for (int jj = 0; jj < 2; ++jj) {
                const half8 bf = *(const half8*)(W2j + (size_t)(jj * 16 + m16) * 256 + kidx);
#pragma unroll
                for (int i = 0; i < 4; ++i)
                    acc[i][jj] = __builtin_amdgcn_mfma_f32_16x16x32_f16(bf, af[i], acc[i][jj], 0, 0, 0);
            }
            __builtin_amdgcn_s_setprio(0);
        }
        if (kc < 3) __syncthreads();   // buf b^1 complete; buf b free to overwrite
    }

    // ---- epilogue: +b2, nontemporal floatx4 stores ----
    // swapped-D layout: lane(m16,quad), reg g holds
    //   out[r0+i*16+m16][wv*32+jj*16+quad*4+g]
    floatx4 b2q[2];
#pragma unroll
    for (int jj = 0; jj < 2; ++jj)
        b2q[jj] = *(const floatx4*)(b2 + wv * 32 + jj * 16 + quad * 4);

    const size_t colbase = (size_t)j * 256 + wv * 32 + quad * 4;
#pragma unroll
    for (int i = 0; i < 4; ++i) {
        float* orow = out + (size_t)(r0 + i * 16 + m16) * OUTROW + colbase;
#pragma unroll
        for (int jj = 0; jj < 2; ++jj) {
            floatx4 v = acc[i][jj] + b2q[jj];
            __builtin_nontemporal_store(v, (floatx4*)(orow + jj * 16));
        }
    }
}

extern "C" void kernel_launch(void* const* d_in, const int* in_sizes, int n_in,
                              void* d_out, int out_size, void* d_ws, size_t ws_size,
                              hipStream_t stream) {
    const float* x    = (const float*)d_in[0];
    const float* W1_3 = (const float*)d_in[1];
    const float* b1_3 = (const float*)d_in[2];
    const float* W2_3 = (const float*)d_in[3];
    const float* b2_3 = (const float*)d_in[4];
    const float* W1_2 = (const float*)d_in[5];
    const float* b1_2 = (const float*)d_in[6];
    const float* W2_2 = (const float*)d_in[7];
    const float* b2_2 = (const float*)d_in[8];
    const float* W1_1 = (const float*)d_in[9];
    const float* b1_1 = (const float*)d_in[10];
    const float* W2_1 = (const float*)d_in[11];
    const float* b2_1 = (const float*)d_in[12];
    float* out = (float*)d_out;
    _Float16* W2t = (_Float16*)d_ws;   // 43*256*256 f16 = 5.64 MB, rebuilt every call

    transpose_w2<<<NJ * 16, 256, 0, stream>>>(W2_3, W2_2, W2_1, W2t);
    motion_main<<<NWG, 512, 0, stream>>>(x, W1_3, b1_3, b2_3,
                                         W1_2, b1_2, b2_2,
                                         W1_1, b1_1, b2_1, W2t, out);
}